// Round 1
// baseline (1027.662 us; speedup 1.0000x reference)
//
#include <hip/hip_runtime.h>
#include <stdint.h>

typedef unsigned short u16;
typedef __bf16 bf16_t;
typedef bf16_t bf16x8 __attribute__((ext_vector_type(8)));
typedef float f32x4 __attribute__((ext_vector_type(4)));
typedef u16 u16x4 __attribute__((ext_vector_type(4)));

#define HIDDEN 4096
#define NTOK 2048
#define NQ 32
#define NKV 8
#define HD 128
#define QKV_N 6144

__device__ __forceinline__ u16 f2bf(float f) {
  union { float f; uint32_t u; } v; v.f = f;
  uint32_t u = v.u;
  return (u16)((u + 0x7fffu + ((u >> 16) & 1u)) >> 16);
}

// ---------------- hidden fp32 -> bf16 ----------------
__global__ void cvt_hidden(const float* __restrict__ src, u16* __restrict__ dst, int n4) {
  int i = blockIdx.x * blockDim.x + threadIdx.x;
  if (i >= n4) return;
  float4 v = ((const float4*)src)[i];
  u16x4 o;
  o[0] = f2bf(v.x); o[1] = f2bf(v.y); o[2] = f2bf(v.z); o[3] = f2bf(v.w);
  ((u16x4*)dst)[i] = o;
}

// ------------- transpose + convert: dst[c][r] = bf16(src[r][c]) -------------
// src: fp32 [R][C], dst: bf16 [C][R]
__global__ void transpose_cvt(const float* __restrict__ src, u16* __restrict__ dst,
                              int R, int C) {
  __shared__ float tile[64][65];
  int tx = threadIdx.x & 63;
  int ty = threadIdx.x >> 6;   // 0..3
  int r0 = blockIdx.y * 64, c0 = blockIdx.x * 64;
  for (int i = 0; i < 16; i++) {
    int r = ty + i * 4;
    tile[r][tx] = src[(size_t)(r0 + r) * C + c0 + tx];
  }
  __syncthreads();
  for (int i = 0; i < 16; i++) {
    int c = ty + i * 4;
    dst[(size_t)(c0 + c) * R + r0 + tx] = f2bf(tile[tx][c]);
  }
}

// ---------------- GEMM: C[M][N] = A[M][K] * B[N][K]^T  (bf16 in, fp32 out) ----------------
// m97 structure: 128x128 tile, BK=32, global_load_lds width 16, 16x16x32 bf16 MFMA
__global__ __launch_bounds__(256) void gemm_bt(const u16* __restrict__ A,
                                               const u16* __restrict__ B,
                                               float* __restrict__ C,
                                               int M, int N, int K) {
  __shared__ u16 sA[128 * 32];
  __shared__ u16 sB[128 * 32];
  const int tid = threadIdx.x;
  const int wave = tid >> 6, lane = tid & 63;
  const int quad = lane >> 4, l16 = lane & 15;
  const int wy = wave >> 1, wx = wave & 1;
  const int row0 = blockIdx.y * 128, col0 = blockIdx.x * 128;
  f32x4 acc[4][4] = {};
  // staging: wave w stages rows w*32 .. w*32+31 (two 16-row calls); lane l -> row l>>2, chunk l&3
  const int srow = wave * 32 + (lane >> 2);
  const int sk = (lane & 3) * 8;
  const u16* gA = A + (size_t)(row0 + srow) * K + sk;
  const u16* gB = B + (size_t)(col0 + srow) * K + sk;
  u16* lA = sA + wave * 32 * 32;
  u16* lB = sB + wave * 32 * 32;
  for (int k0 = 0; k0 < K; k0 += 32) {
    __builtin_amdgcn_global_load_lds(
        (__attribute__((address_space(1))) void*)(void*)(gA + k0),
        (__attribute__((address_space(3))) void*)(void*)lA, 16, 0, 0);
    __builtin_amdgcn_global_load_lds(
        (__attribute__((address_space(1))) void*)(void*)(gA + k0 + (size_t)16 * K),
        (__attribute__((address_space(3))) void*)(void*)(lA + 16 * 32), 16, 0, 0);
    __builtin_amdgcn_global_load_lds(
        (__attribute__((address_space(1))) void*)(void*)(gB + k0),
        (__attribute__((address_space(3))) void*)(void*)lB, 16, 0, 0);
    __builtin_amdgcn_global_load_lds(
        (__attribute__((address_space(1))) void*)(void*)(gB + k0 + (size_t)16 * K),
        (__attribute__((address_space(3))) void*)(void*)(lB + 16 * 32), 16, 0, 0);
    __syncthreads();
    bf16x8 af[4], bfr[4];
    for (int mi = 0; mi < 4; mi++)
      af[mi] = *(const bf16x8*)(const void*)(sA + (wy * 64 + mi * 16 + l16) * 32 + quad * 8);
    for (int ni = 0; ni < 4; ni++)
      bfr[ni] = *(const bf16x8*)(const void*)(sB + (wx * 64 + ni * 16 + l16) * 32 + quad * 8);
    for (int mi = 0; mi < 4; mi++)
      for (int ni = 0; ni < 4; ni++)
        acc[mi][ni] = __builtin_amdgcn_mfma_f32_16x16x32_bf16(af[mi], bfr[ni], acc[mi][ni], 0, 0, 0);
    __syncthreads();
  }
  for (int mi = 0; mi < 4; mi++)
    for (int ni = 0; ni < 4; ni++) {
      int row = row0 + wy * 64 + mi * 16 + quad * 4;
      int col = col0 + wx * 64 + ni * 16 + l16;
      float* cp = C + (size_t)row * N + col;
      for (int r = 0; r < 4; r++) cp[(size_t)r * N] = acc[mi][ni][r];
    }
}

// ---------------- RMSNorm + RoPE for Q and K heads ----------------
// grid: (40, 2048), 64 threads. hh<32 -> Q head, else K head (hh-32)
__global__ void normrope(const float* __restrict__ qkv, const int* __restrict__ pos,
                         const float* __restrict__ qw, const float* __restrict__ kw,
                         u16* __restrict__ Qo, u16* __restrict__ Ko) {
  const int hh = blockIdx.x;
  const int t = blockIdx.y;
  const int lane = threadIdx.x;  // 0..63
  const bool isQ = hh < NQ;
  const int col = isQ ? hh * HD : HIDDEN + (hh - NQ) * HD;
  const float* src = qkv + (size_t)t * QKV_N + col;
  float x1 = src[lane], x2 = src[lane + 64];
  float ss = x1 * x1 + x2 * x2;
  for (int m = 1; m < 64; m <<= 1) ss += __shfl_xor(ss, m);
  float inv = rsqrtf(ss * (1.0f / 128.0f) + 1e-6f);
  const float* w = isQ ? qw : kw;
  x1 *= inv * w[lane];
  x2 *= inv * w[lane + 64];
  float p = (float)pos[t];
  // inv_freq = 1e6^(-lane/64) = exp(-lane * ln(1e6)/64)
  float freq = expf((float)lane * -0.2158673525f);
  float a = p * freq;
  float sn = sinf(a), cs = cosf(a);
  float o1 = x1 * cs - x2 * sn;
  float o2 = x2 * cs + x1 * sn;
  u16* dst = isQ ? (Qo + (size_t)t * (NQ * HD) + hh * HD)
                 : (Ko + (size_t)t * (NKV * HD) + (hh - NQ) * HD);
  dst[lane] = f2bf(o1);
  dst[lane + 64] = f2bf(o2);
}

// ---------------- V: fp32 [t][5120+vh*128+d] -> bf16 vT[vh][d][t] ----------------
__global__ void vtrans(const float* __restrict__ qkv, u16* __restrict__ vT) {
  __shared__ float s[128][65];
  int tb = blockIdx.x;   // 0..31 (64-token block)
  int vh = blockIdx.y;   // 0..7
  int tid = threadIdx.x; // 256
  for (int i = 0; i < 32; i++) {
    int e = i * 256 + tid;
    int tl = e >> 7;      // 0..63
    int d = e & 127;
    s[d][tl] = qkv[(size_t)(tb * 64 + tl) * QKV_N + 5120 + vh * 128 + d];
  }
  __syncthreads();
  for (int i = 0; i < 32; i++) {
    int e = i * 256 + tid;
    int d = e >> 6;       // 0..127
    int tl = e & 63;
    vT[(size_t)vh * (HD * NTOK) + (size_t)d * NTOK + tb * 64 + tl] = f2bf(s[d][tl]);
  }
}

// ---------------- flash attention (causal, GQA 4:1) ----------------
// grid (16 qblocks, 32 heads), 512 threads = 8 waves, each wave owns 16 q rows
__global__ __launch_bounds__(512) void flash(const u16* __restrict__ Q,
                                             const u16* __restrict__ Kb,
                                             const u16* __restrict__ Vt,
                                             u16* __restrict__ O) {
  __shared__ u16 sP[8][16 * 136];
  const int qb = blockIdx.x, h = blockIdx.y;
  const int kvh = h >> 2;
  const int tid = threadIdx.x;
  const int wave = tid >> 6, lane = tid & 63;
  const int quad = lane >> 4, l16 = lane & 15;
  const int qrow0 = qb * 128 + wave * 16;
  const float scale = 0.08838834764831845f;  // 1/sqrt(128)
  bf16x8 qf[4];
  for (int ks = 0; ks < 4; ks++)
    qf[ks] = *(const bf16x8*)(const void*)(Q + (size_t)(qrow0 + l16) * (NQ * HD) + h * HD + ks * 32 + quad * 8);
  f32x4 accO[8] = {};
  float m_i[4], l_i[4];
  for (int r = 0; r < 4; r++) { m_i[r] = -1e30f; l_i[r] = 0.f; }
  u16* myP = &sP[wave][0];
  for (int kb = 0; kb <= qb; kb++) {
    f32x4 s[8] = {};
    for (int ks = 0; ks < 4; ks++)
      for (int nt = 0; nt < 8; nt++) {
        bf16x8 kf = *(const bf16x8*)(const void*)(Kb + (size_t)(kb * 128 + nt * 16 + l16) * (NKV * HD) + kvh * HD + ks * 32 + quad * 8);
        s[nt] = __builtin_amdgcn_mfma_f32_16x16x32_bf16(qf[ks], kf, s[nt], 0, 0, 0);
      }
    const bool diag = (kb == qb);
    float mx[4] = {-1e30f, -1e30f, -1e30f, -1e30f};
    for (int nt = 0; nt < 8; nt++)
      for (int r = 0; r < 4; r++) {
        float sv = s[nt][r] * scale;
        if (diag && (nt * 16 + l16) > (wave * 16 + quad * 4 + r)) sv = -1e30f;
        s[nt][r] = sv;
        mx[r] = fmaxf(mx[r], sv);
      }
    float alpha[4], rs[4];
    for (int r = 0; r < 4; r++) {
      float m = mx[r];
      m = fmaxf(m, __shfl_xor(m, 1));
      m = fmaxf(m, __shfl_xor(m, 2));
      m = fmaxf(m, __shfl_xor(m, 4));
      m = fmaxf(m, __shfl_xor(m, 8));
      float mn = fmaxf(m_i[r], m);
      alpha[r] = __expf(m_i[r] - mn);
      m_i[r] = mn;
      rs[r] = 0.f;
    }
    for (int nt = 0; nt < 8; nt++)
      for (int r = 0; r < 4; r++) {
        float p = __expf(s[nt][r] - m_i[r]);
        rs[r] += p;
        myP[(quad * 4 + r) * 136 + nt * 16 + l16] = f2bf(p);
      }
    for (int r = 0; r < 4; r++) {
      float t = rs[r];
      t += __shfl_xor(t, 1);
      t += __shfl_xor(t, 2);
      t += __shfl_xor(t, 4);
      t += __shfl_xor(t, 8);
      l_i[r] = l_i[r] * alpha[r] + t;
    }
    for (int nt = 0; nt < 8; nt++)
      for (int r = 0; r < 4; r++) accO[nt][r] *= alpha[r];
    asm volatile("s_waitcnt lgkmcnt(0)" ::: "memory");
    for (int ks = 0; ks < 4; ks++) {
      bf16x8 pf = *(const bf16x8*)(const void*)(myP + l16 * 136 + ks * 32 + quad * 8);
      for (int nt = 0; nt < 8; nt++) {
        bf16x8 vf = *(const bf16x8*)(const void*)(Vt + (size_t)kvh * (HD * NTOK) + (size_t)(nt * 16 + l16) * NTOK + kb * 128 + ks * 32 + quad * 8);
        accO[nt] = __builtin_amdgcn_mfma_f32_16x16x32_bf16(pf, vf, accO[nt], 0, 0, 0);
      }
    }
  }
  for (int r = 0; r < 4; r++) {
    float inv = 1.0f / l_i[r];
    int t = qb * 128 + wave * 16 + quad * 4 + r;
    for (int nt = 0; nt < 8; nt++)
      O[(size_t)t * (NQ * HD) + h * HD + nt * 16 + l16] = f2bf(accO[nt][r] * inv);
  }
}

extern "C" void kernel_launch(void* const* d_in, const int* in_sizes, int n_in,
                              void* d_out, int out_size, void* d_ws, size_t ws_size,
                              hipStream_t stream) {
  const float* hidden = (const float*)d_in[0];
  const int* positions = (const int*)d_in[1];
  const float* Wq = (const float*)d_in[2];
  const float* Wk = (const float*)d_in[3];
  const float* Wv = (const float*)d_in[4];
  const float* Wo = (const float*)d_in[5];
  const float* qw = (const float*)d_in[6];
  const float* kw = (const float*)d_in[7];
  char* ws = (char*)d_ws;
  // workspace layout (bytes)
  u16* hid_bf  = (u16*)(ws);                    // 2048*4096*2  = 16 MB
  u16* WqkvT   = (u16*)(ws + 16777216);         // 6144*4096*2  = 48 MB
  u16* WoT     = (u16*)(ws + 67108864);         // 4096*4096*2  = 32 MB
  float* qkvf  = (float*)(ws + 100663296);      // 2048*6144*4  = 48 MB
  u16* Qn      = (u16*)(ws + 150994944);        // 2048*4096*2  = 16 MB
  u16* Kn      = (u16*)(ws + 167772160);        // 2048*1024*2  =  4 MB
  u16* Vt      = (u16*)(ws + 171966464);        // 8*128*2048*2 =  4 MB
  u16* AO      = (u16*)(ws + 176160768);        // 2048*4096*2  = 16 MB
  float* outp  = (float*)d_out;

  cvt_hidden<<<NTOK * HIDDEN / 4 / 256, 256, 0, stream>>>(hidden, hid_bf, NTOK * HIDDEN / 4);
  transpose_cvt<<<dim3(64, 64), 256, 0, stream>>>(Wq, WqkvT, 4096, 4096);
  transpose_cvt<<<dim3(16, 64), 256, 0, stream>>>(Wk, WqkvT + (size_t)4096 * 4096, 4096, 1024);
  transpose_cvt<<<dim3(16, 64), 256, 0, stream>>>(Wv, WqkvT + (size_t)5120 * 4096, 4096, 1024);
  transpose_cvt<<<dim3(64, 64), 256, 0, stream>>>(Wo, WoT, 4096, 4096);
  gemm_bt<<<dim3(48, 16), 256, 0, stream>>>(hid_bf, WqkvT, qkvf, 2048, 6144, 4096);
  normrope<<<dim3(40, 2048), 64, 0, stream>>>(qkvf, positions, qw, kw, Qn, Kn);
  vtrans<<<dim3(32, 8), 256, 0, stream>>>(qkvf, Vt);
  flash<<<dim3(16, 32), 512, 0, stream>>>(Qn, Kn, Vt, AO);
  gemm_bt<<<dim3(32, 16), 256, 0, stream>>>(AO, WoT, outp, 2048, 4096, 4096);
}

// Round 2
// 567.092 us; speedup vs baseline: 1.8122x; 1.8122x over previous
//
#include <hip/hip_runtime.h>
#include <stdint.h>

typedef unsigned short u16;
typedef __bf16 bf16_t;
typedef bf16_t bf16x8 __attribute__((ext_vector_type(8)));
typedef float f32x4 __attribute__((ext_vector_type(4)));
typedef u16 u16x4 __attribute__((ext_vector_type(4)));
typedef u16 u16x8 __attribute__((ext_vector_type(8)));

#define HIDDEN 4096
#define NTOK 2048
#define NQ 32
#define NKV 8
#define HD 128
#define QKV_N 6144

__device__ __forceinline__ u16 f2bf(float f) {
  union { float f; uint32_t u; } v; v.f = f;
  uint32_t u = v.u;
  return (u16)((u + 0x7fffu + ((u >> 16) & 1u)) >> 16);
}

// ---------------- hidden fp32 -> bf16 ----------------
__global__ void cvt_hidden(const float* __restrict__ src, u16* __restrict__ dst, int n4) {
  int i = blockIdx.x * blockDim.x + threadIdx.x;
  if (i >= n4) return;
  float4 v = ((const float4*)src)[i];
  u16x4 o;
  o[0] = f2bf(v.x); o[1] = f2bf(v.y); o[2] = f2bf(v.z); o[3] = f2bf(v.w);
  ((u16x4*)dst)[i] = o;
}

// ------------- transpose + convert: dst[c][r] = bf16(src[r][c]) -------------
__global__ void transpose_cvt(const float* __restrict__ src, u16* __restrict__ dst,
                              int R, int C) {
  __shared__ float tile[64][65];
  int tx = threadIdx.x & 63;
  int ty = threadIdx.x >> 6;   // 0..3
  int r0 = blockIdx.y * 64, c0 = blockIdx.x * 64;
  for (int i = 0; i < 16; i++) {
    int r = ty + i * 4;
    tile[r][tx] = src[(size_t)(r0 + r) * C + c0 + tx];
  }
  __syncthreads();
  for (int i = 0; i < 16; i++) {
    int c = ty + i * 4;
    dst[(size_t)(c0 + c) * R + r0 + tx] = f2bf(tile[tx][c]);
  }
}

// ---------------- GEMM: C[M][N] = A[M][K] * B[N][K]^T  (bf16 in, fp32 out) ----------------
__global__ __launch_bounds__(256) void gemm_bt(const u16* __restrict__ A,
                                               const u16* __restrict__ B,
                                               float* __restrict__ C,
                                               int M, int N, int K) {
  __shared__ u16 sA[128 * 32];
  __shared__ u16 sB[128 * 32];
  const int tid = threadIdx.x;
  const int wave = tid >> 6, lane = tid & 63;
  const int quad = lane >> 4, l16 = lane & 15;
  const int wy = wave >> 1, wx = wave & 1;
  const int row0 = blockIdx.y * 128, col0 = blockIdx.x * 128;
  f32x4 acc[4][4] = {};
  const int srow = wave * 32 + (lane >> 2);
  const int sk = (lane & 3) * 8;
  const u16* gA = A + (size_t)(row0 + srow) * K + sk;
  const u16* gB = B + (size_t)(col0 + srow) * K + sk;
  u16* lA = sA + wave * 32 * 32;
  u16* lB = sB + wave * 32 * 32;
  for (int k0 = 0; k0 < K; k0 += 32) {
    __builtin_amdgcn_global_load_lds(
        (__attribute__((address_space(1))) void*)(void*)(gA + k0),
        (__attribute__((address_space(3))) void*)(void*)lA, 16, 0, 0);
    __builtin_amdgcn_global_load_lds(
        (__attribute__((address_space(1))) void*)(void*)(gA + k0 + (size_t)16 * K),
        (__attribute__((address_space(3))) void*)(void*)(lA + 16 * 32), 16, 0, 0);
    __builtin_amdgcn_global_load_lds(
        (__attribute__((address_space(1))) void*)(void*)(gB + k0),
        (__attribute__((address_space(3))) void*)(void*)lB, 16, 0, 0);
    __builtin_amdgcn_global_load_lds(
        (__attribute__((address_space(1))) void*)(void*)(gB + k0 + (size_t)16 * K),
        (__attribute__((address_space(3))) void*)(void*)(lB + 16 * 32), 16, 0, 0);
    __syncthreads();
    bf16x8 af[4], bfr[4];
    for (int mi = 0; mi < 4; mi++)
      af[mi] = *(const bf16x8*)(const void*)(sA + (wy * 64 + mi * 16 + l16) * 32 + quad * 8);
    for (int ni = 0; ni < 4; ni++)
      bfr[ni] = *(const bf16x8*)(const void*)(sB + (wx * 64 + ni * 16 + l16) * 32 + quad * 8);
    for (int mi = 0; mi < 4; mi++)
      for (int ni = 0; ni < 4; ni++)
        acc[mi][ni] = __builtin_amdgcn_mfma_f32_16x16x32_bf16(af[mi], bfr[ni], acc[mi][ni], 0, 0, 0);
    __syncthreads();
  }
  for (int mi = 0; mi < 4; mi++)
    for (int ni = 0; ni < 4; ni++) {
      int row = row0 + wy * 64 + mi * 16 + quad * 4;
      int col = col0 + wx * 64 + ni * 16 + l16;
      float* cp = C + (size_t)row * N + col;
      for (int r = 0; r < 4; r++) cp[(size_t)r * N] = acc[mi][ni][r];
    }
}

// ---------------- RMSNorm + RoPE for Q and K heads (Q pre-scaled by 1/sqrt(HD)) ----------------
__global__ void normrope(const float* __restrict__ qkv, const int* __restrict__ pos,
                         const float* __restrict__ qw, const float* __restrict__ kw,
                         u16* __restrict__ Qo, u16* __restrict__ Ko) {
  const int hh = blockIdx.x;
  const int t = blockIdx.y;
  const int lane = threadIdx.x;  // 0..63
  const bool isQ = hh < NQ;
  const int col = isQ ? hh * HD : HIDDEN + (hh - NQ) * HD;
  const float* src = qkv + (size_t)t * QKV_N + col;
  float x1 = src[lane], x2 = src[lane + 64];
  float ss = x1 * x1 + x2 * x2;
  for (int m = 1; m < 64; m <<= 1) ss += __shfl_xor(ss, m);
  float inv = rsqrtf(ss * (1.0f / 128.0f) + 1e-6f);
  const float* w = isQ ? qw : kw;
  x1 *= inv * w[lane];
  x2 *= inv * w[lane + 64];
  float p = (float)pos[t];
  float freq = expf((float)lane * -0.2158673525f);
  float a = p * freq;
  float sn = sinf(a), cs = cosf(a);
  float o1 = x1 * cs - x2 * sn;
  float o2 = x2 * cs + x1 * sn;
  const float osc = isQ ? 0.08838834764831845f : 1.0f;  // fold 1/sqrt(128) into Q
  u16* dst = isQ ? (Qo + (size_t)t * (NQ * HD) + hh * HD)
                 : (Ko + (size_t)t * (NKV * HD) + (hh - NQ) * HD);
  dst[lane] = f2bf(o1 * osc);
  dst[lane + 64] = f2bf(o2 * osc);
}

// ---------------- V: fp32 [t][5120+vh*128+d] -> bf16 vT[vh][d][t] ----------------
__global__ void vtrans(const float* __restrict__ qkv, u16* __restrict__ vT) {
  __shared__ float s[128][65];
  int tb = blockIdx.x;   // 0..31 (64-token block)
  int vh = blockIdx.y;   // 0..7
  int tid = threadIdx.x; // 256
  for (int i = 0; i < 32; i++) {
    int e = i * 256 + tid;
    int tl = e >> 7;
    int d = e & 127;
    s[d][tl] = qkv[(size_t)(tb * 64 + tl) * QKV_N + 5120 + vh * 128 + d];
  }
  __syncthreads();
  for (int i = 0; i < 32; i++) {
    int e = i * 256 + tid;
    int d = e >> 6;
    int tl = e & 63;
    vT[(size_t)vh * (HD * NTOK) + (size_t)d * NTOK + tb * 64 + tl] = f2bf(s[d][tl]);
  }
}

// ---------------- flash attention v2: LDS-staged K/V, paired q-tiles, shift-softmax ----------------
// grid (8 pairs, 32 heads), 512 threads = 8 waves x 16 q-rows.
// Block p handles q-tiles {p, 15-p}: exactly 34 64-token units each -> perfect balance.
__global__ __launch_bounds__(512) void flash2(const u16* __restrict__ Q,
                                              const u16* __restrict__ K,
                                              const u16* __restrict__ V,
                                              u16* __restrict__ O) {
  __shared__ u16 sK[64 * 136];       // [token][d] pad->136 (2-way free on b128 frag reads)
  __shared__ u16 sV[128 * 72];       // [d][token] pad->72
  __shared__ u16 sP[8][16 * 72];     // per-wave P, [qrow][token] pad->72
  const int p = blockIdx.x, h = blockIdx.y, kvh = h >> 2;
  const int tid = threadIdx.x;
  const int wave = tid >> 6, lane = tid & 63;
  const int quad = lane >> 4, l16 = lane & 15;
  u16* myP = &sP[wave][0];
  const u16* Vh = V + (size_t)kvh * (HD * NTOK);
  const int qtiles[2] = {p, 15 - p};
  // staging coords (fixed per thread)
  const int rk0 = tid >> 4, ck0 = tid & 15;        // sK: rows 0..31, cols 0..15 (16B)
  const int rv0 = tid >> 3, cv0 = tid & 7;         // sV: rows 0..63, cols 0..7 (16B)
  for (int ti = 0; ti < 2; ti++) {
    const int qb = qtiles[ti];
    const int qrow0 = qb * 128 + wave * 16;
    bf16x8 qf[4];
    for (int ks = 0; ks < 4; ks++)
      qf[ks] = *(const bf16x8*)(const void*)(Q + (size_t)(qrow0 + l16) * (NQ * HD) + h * HD + ks * 32 + quad * 8);
    f32x4 accO[8] = {};
    float l_r[4] = {0.f, 0.f, 0.f, 0.f};
    const int nU = 2 * (qb + 1);
    const int myMax = (qrow0 + 15) >> 6;  // last unit with any unmasked token for this wave
    for (int kb = 0; kb < nU; kb++) {
      // global loads for next tile (before barrier, hides latency)
      u16x8 k0 = *(const u16x8*)(const void*)(K + (size_t)(kb * 64 + rk0) * (NKV * HD) + kvh * HD + ck0 * 8);
      u16x8 k1 = *(const u16x8*)(const void*)(K + (size_t)(kb * 64 + rk0 + 32) * (NKV * HD) + kvh * HD + ck0 * 8);
      u16x8 v0 = *(const u16x8*)(const void*)(Vh + (size_t)rv0 * NTOK + kb * 64 + cv0 * 8);
      u16x8 v1 = *(const u16x8*)(const void*)(Vh + (size_t)(rv0 + 64) * NTOK + kb * 64 + cv0 * 8);
      __syncthreads();   // previous unit's LDS reads complete
      *(u16x8*)(void*)(sK + rk0 * 136 + ck0 * 8) = k0;
      *(u16x8*)(void*)(sK + (rk0 + 32) * 136 + ck0 * 8) = k1;
      *(u16x8*)(void*)(sV + rv0 * 72 + cv0 * 8) = v0;
      *(u16x8*)(void*)(sV + (rv0 + 64) * 72 + cv0 * 8) = v1;
      __syncthreads();
      if (kb <= myMax) {
        // S = Q K^T for 16 q-rows x 64 tokens
        f32x4 s[4] = {};
        for (int ks = 0; ks < 4; ks++)
          for (int nt = 0; nt < 4; nt++) {
            bf16x8 kf = *(const bf16x8*)(const void*)(sK + (nt * 16 + l16) * 136 + ks * 32 + quad * 8);
            s[nt] = __builtin_amdgcn_mfma_f32_16x16x32_bf16(qf[ks], kf, s[nt], 0, 0, 0);
          }
        // shift-free softmax accumulate (scores ~N(0,1): exp is fp32-safe)
        const int qg = qrow0 + quad * 4;
        for (int nt = 0; nt < 4; nt++) {
          int tok = kb * 64 + nt * 16 + l16;
          for (int r = 0; r < 4; r++) {
            float e = __expf(s[nt][r]);
            float pv = (tok <= qg + r) ? e : 0.0f;
            l_r[r] += pv;
            myP[(quad * 4 + r) * 72 + nt * 16 + l16] = f2bf(pv);
          }
        }
        asm volatile("s_waitcnt lgkmcnt(0)" ::: "memory");
        // O += P V
        for (int ks = 0; ks < 2; ks++) {
          bf16x8 pf = *(const bf16x8*)(const void*)(myP + l16 * 72 + ks * 32 + quad * 8);
          for (int nt = 0; nt < 8; nt++) {
            bf16x8 vf = *(const bf16x8*)(const void*)(sV + (nt * 16 + l16) * 72 + ks * 32 + quad * 8);
            accO[nt] = __builtin_amdgcn_mfma_f32_16x16x32_bf16(pf, vf, accO[nt], 0, 0, 0);
          }
        }
      }
    }
    // epilogue: reduce l over the 16 token-lanes, normalize, store
    float inv[4];
    for (int r = 0; r < 4; r++) {
      float t = l_r[r];
      t += __shfl_xor(t, 1);
      t += __shfl_xor(t, 2);
      t += __shfl_xor(t, 4);
      t += __shfl_xor(t, 8);
      inv[r] = 1.0f / t;
    }
    for (int nt = 0; nt < 8; nt++)
      for (int r = 0; r < 4; r++)
        O[(size_t)(qrow0 + quad * 4 + r) * (NQ * HD) + h * HD + nt * 16 + l16] =
            f2bf(accO[nt][r] * inv[r]);
  }
}

extern "C" void kernel_launch(void* const* d_in, const int* in_sizes, int n_in,
                              void* d_out, int out_size, void* d_ws, size_t ws_size,
                              hipStream_t stream) {
  const float* hidden = (const float*)d_in[0];
  const int* positions = (const int*)d_in[1];
  const float* Wq = (const float*)d_in[2];
  const float* Wk = (const float*)d_in[3];
  const float* Wv = (const float*)d_in[4];
  const float* Wo = (const float*)d_in[5];
  const float* qw = (const float*)d_in[6];
  const float* kw = (const float*)d_in[7];
  char* ws = (char*)d_ws;
  u16* hid_bf  = (u16*)(ws);                    // 16 MB
  u16* WqkvT   = (u16*)(ws + 16777216);         // 48 MB
  u16* WoT     = (u16*)(ws + 67108864);         // 32 MB
  float* qkvf  = (float*)(ws + 100663296);      // 48 MB
  u16* Qn      = (u16*)(ws + 150994944);        // 16 MB
  u16* Kn      = (u16*)(ws + 167772160);        //  4 MB
  u16* Vt      = (u16*)(ws + 171966464);        //  4 MB
  u16* AO      = (u16*)(ws + 176160768);        // 16 MB
  float* outp  = (float*)d_out;

  cvt_hidden<<<NTOK * HIDDEN / 4 / 256, 256, 0, stream>>>(hidden, hid_bf, NTOK * HIDDEN / 4);
  transpose_cvt<<<dim3(64, 64), 256, 0, stream>>>(Wq, WqkvT, 4096, 4096);
  transpose_cvt<<<dim3(16, 64), 256, 0, stream>>>(Wk, WqkvT + (size_t)4096 * 4096, 4096, 1024);
  transpose_cvt<<<dim3(16, 64), 256, 0, stream>>>(Wv, WqkvT + (size_t)5120 * 4096, 4096, 1024);
  transpose_cvt<<<dim3(64, 64), 256, 0, stream>>>(Wo, WoT, 4096, 4096);
  gemm_bt<<<dim3(48, 16), 256, 0, stream>>>(hid_bf, WqkvT, qkvf, 2048, 6144, 4096);
  normrope<<<dim3(40, 2048), 64, 0, stream>>>(qkvf, positions, qw, kw, Qn, Kn);
  vtrans<<<dim3(32, 8), 256, 0, stream>>>(qkvf, Vt);
  flash2<<<dim3(8, 32), 512, 0, stream>>>(Qn, Kn, Vt, AO);
  gemm_bt<<<dim3(32, 16), 256, 0, stream>>>(AO, WoT, outp, 2048, 4096, 4096);
}

// Round 3
// 502.289 us; speedup vs baseline: 2.0460x; 1.1290x over previous
//
#include <hip/hip_runtime.h>
#include <stdint.h>

typedef unsigned short u16;
typedef __bf16 bf16_t;
typedef bf16_t bf16x8 __attribute__((ext_vector_type(8)));
typedef float f32x4 __attribute__((ext_vector_type(4)));
typedef u16 u16x4 __attribute__((ext_vector_type(4)));
typedef u16 u16x8 __attribute__((ext_vector_type(8)));

#define HIDDEN 4096
#define NTOK 2048
#define NQ 32
#define NKV 8
#define HD 128
#define QKV_N 6144

#define AS1 __attribute__((address_space(1)))
#define AS3 __attribute__((address_space(3)))

__device__ __forceinline__ u16 f2bf(float f) {
  union { float f; uint32_t u; } v; v.f = f;
  uint32_t u = v.u;
  return (u16)((u + 0x7fffu + ((u >> 16) & 1u)) >> 16);
}

// ---------------- hidden fp32 -> bf16 ----------------
__global__ void cvt_hidden(const float* __restrict__ src, u16* __restrict__ dst, int n4) {
  int i = blockIdx.x * blockDim.x + threadIdx.x;
  if (i >= n4) return;
  float4 v = ((const float4*)src)[i];
  u16x4 o;
  o[0] = f2bf(v.x); o[1] = f2bf(v.y); o[2] = f2bf(v.z); o[3] = f2bf(v.w);
  ((u16x4*)dst)[i] = o;
}

// ------------- transpose + convert: dst[c][r] = bf16(src[r][c]) -------------
__global__ void transpose_cvt(const float* __restrict__ src, u16* __restrict__ dst,
                              int R, int C) {
  __shared__ float tile[64][65];
  int tx = threadIdx.x & 63;
  int ty = threadIdx.x >> 6;   // 0..3
  int r0 = blockIdx.y * 64, c0 = blockIdx.x * 64;
  for (int i = 0; i < 16; i++) {
    int r = ty + i * 4;
    tile[r][tx] = src[(size_t)(r0 + r) * C + c0 + tx];
  }
  __syncthreads();
  for (int i = 0; i < 16; i++) {
    int c = ty + i * 4;
    dst[(size_t)(c0 + c) * R + r0 + tx] = f2bf(tile[tx][c]);
  }
}

// ---------------- GEMM: C[M][N] = A[M][K] * B[N][K]^T  (bf16 in, fp32 out) ----------------
// BK=64, XOR-swizzled LDS chunk layout (conflict-free b128 fragment reads),
// global_load_lds width-16 staging, 16x16x32 bf16 MFMA, 64x64 per wave.
__global__ __launch_bounds__(256, 3) void gemm_bt(const u16* __restrict__ A,
                                                  const u16* __restrict__ B,
                                                  float* __restrict__ C,
                                                  int M, int N, int K) {
  __shared__ u16 sA[128 * 64];
  __shared__ u16 sB[128 * 64];
  const int tid = threadIdx.x;
  const int wave = tid >> 6, lane = tid & 63;
  const int quad = lane >> 4, l16 = lane & 15;
  const int wy = wave >> 1, wx = wave & 1;
  const int row0 = blockIdx.y * 128, col0 = blockIdx.x * 128;
  f32x4 acc[4][4] = {};
  // staging: each wave stages 32 rows of A and 32 rows of B (4 calls x 8 rows each).
  // lane -> local row lr=lane>>3, LDS chunk lane&7 holds global chunk (lane&7)^lr.
  const int lr = lane >> 3;
  const int sc = (lane & 7) ^ lr;
  const u16* gA = A + (size_t)(row0 + wave * 32 + lr) * K + sc * 8;
  const u16* gB = B + (size_t)(col0 + wave * 32 + lr) * K + sc * 8;
  u16* lA = sA + wave * 32 * 64;
  u16* lB = sB + wave * 32 * 64;
  // fragment read addresses (loop-invariant): global chunk q at LDS chunk q^(row&7)
  const int swz = l16 & 7;
  for (int k0 = 0; k0 < K; k0 += 64) {
    for (int j = 0; j < 4; j++) {
      __builtin_amdgcn_global_load_lds(
          (AS1 void*)(void*)(gA + k0 + (size_t)(j * 8) * K),
          (AS3 void*)(void*)(lA + j * 8 * 64), 16, 0, 0);
      __builtin_amdgcn_global_load_lds(
          (AS1 void*)(void*)(gB + k0 + (size_t)(j * 8) * K),
          (AS3 void*)(void*)(lB + j * 8 * 64), 16, 0, 0);
    }
    __syncthreads();
    bf16x8 af[2][4], bfr[2][4];
    for (int s = 0; s < 2; s++)
      for (int mi = 0; mi < 4; mi++) {
        const int c = ((s * 4 + quad) ^ swz) * 8;
        af[s][mi] = *(const bf16x8*)(const void*)(sA + (wy * 64 + mi * 16 + l16) * 64 + c);
        bfr[s][mi] = *(const bf16x8*)(const void*)(sB + (wx * 64 + mi * 16 + l16) * 64 + c);
      }
    for (int s = 0; s < 2; s++)
      for (int mi = 0; mi < 4; mi++)
        for (int ni = 0; ni < 4; ni++)
          acc[mi][ni] = __builtin_amdgcn_mfma_f32_16x16x32_bf16(af[s][mi], bfr[s][ni], acc[mi][ni], 0, 0, 0);
    __syncthreads();
  }
  for (int mi = 0; mi < 4; mi++)
    for (int ni = 0; ni < 4; ni++) {
      int row = row0 + wy * 64 + mi * 16 + quad * 4;
      int col = col0 + wx * 64 + ni * 16 + l16;
      float* cp = C + (size_t)row * N + col;
      for (int r = 0; r < 4; r++) cp[(size_t)r * N] = acc[mi][ni][r];
    }
}

// ---------------- RMSNorm + RoPE for Q and K heads (Q pre-scaled by 1/sqrt(HD)) ----------------
// 256 threads = 4 token-units per block; grid (40, 512)
__global__ void normrope(const float* __restrict__ qkv, const int* __restrict__ pos,
                         const float* __restrict__ qw, const float* __restrict__ kw,
                         u16* __restrict__ Qo, u16* __restrict__ Ko) {
  const int hh = blockIdx.x;
  const int t = blockIdx.y * 4 + (threadIdx.x >> 6);
  const int lane = threadIdx.x & 63;
  const bool isQ = hh < NQ;
  const int col = isQ ? hh * HD : HIDDEN + (hh - NQ) * HD;
  const float* src = qkv + (size_t)t * QKV_N + col;
  float x1 = src[lane], x2 = src[lane + 64];
  float ss = x1 * x1 + x2 * x2;
  for (int m = 1; m < 64; m <<= 1) ss += __shfl_xor(ss, m);
  float inv = rsqrtf(ss * (1.0f / 128.0f) + 1e-6f);
  const float* w = isQ ? qw : kw;
  x1 *= inv * w[lane];
  x2 *= inv * w[lane + 64];
  float p = (float)pos[t];
  float freq = expf((float)lane * -0.2158673525f);
  float a = p * freq;
  float sn = sinf(a), cs = cosf(a);
  float o1 = x1 * cs - x2 * sn;
  float o2 = x2 * cs + x1 * sn;
  const float osc = isQ ? 0.08838834764831845f : 1.0f;  // fold 1/sqrt(128) into Q
  u16* dst = isQ ? (Qo + (size_t)t * (NQ * HD) + hh * HD)
                 : (Ko + (size_t)t * (NKV * HD) + (hh - NQ) * HD);
  dst[lane] = f2bf(o1 * osc);
  dst[lane + 64] = f2bf(o2 * osc);
}

// ---------------- V: fp32 [t][5120+vh*128+d] -> bf16 vT[vh][d][t] ----------------
__global__ void vtrans(const float* __restrict__ qkv, u16* __restrict__ vT) {
  __shared__ float s[128][65];
  int tb = blockIdx.x;   // 0..31 (64-token block)
  int vh = blockIdx.y;   // 0..7
  int tid = threadIdx.x; // 256
  for (int i = 0; i < 32; i++) {
    int e = i * 256 + tid;
    int tl = e >> 7;
    int d = e & 127;
    s[d][tl] = qkv[(size_t)(tb * 64 + tl) * QKV_N + 5120 + vh * 128 + d];
  }
  __syncthreads();
  for (int i = 0; i < 32; i++) {
    int e = i * 256 + tid;
    int d = e >> 6;
    int tl = e & 63;
    vT[(size_t)vh * (HD * NTOK) + (size_t)d * NTOK + tb * 64 + tl] = f2bf(s[d][tl]);
  }
}

// ---------------- flash attention: LDS-staged K/V, paired q-tiles, shift-softmax ----------------
__global__ __launch_bounds__(512) void flash2(const u16* __restrict__ Q,
                                              const u16* __restrict__ K,
                                              const u16* __restrict__ V,
                                              u16* __restrict__ O) {
  __shared__ u16 sK[64 * 136];
  __shared__ u16 sV[128 * 72];
  __shared__ u16 sP[8][16 * 72];
  const int p = blockIdx.x, h = blockIdx.y, kvh = h >> 2;
  const int tid = threadIdx.x;
  const int wave = tid >> 6, lane = tid & 63;
  const int quad = lane >> 4, l16 = lane & 15;
  u16* myP = &sP[wave][0];
  const u16* Vh = V + (size_t)kvh * (HD * NTOK);
  const int qtiles[2] = {p, 15 - p};
  const int rk0 = tid >> 4, ck0 = tid & 15;
  const int rv0 = tid >> 3, cv0 = tid & 7;
  for (int ti = 0; ti < 2; ti++) {
    const int qb = qtiles[ti];
    const int qrow0 = qb * 128 + wave * 16;
    bf16x8 qf[4];
    for (int ks = 0; ks < 4; ks++)
      qf[ks] = *(const bf16x8*)(const void*)(Q + (size_t)(qrow0 + l16) * (NQ * HD) + h * HD + ks * 32 + quad * 8);
    f32x4 accO[8] = {};
    float l_r[4] = {0.f, 0.f, 0.f, 0.f};
    const int nU = 2 * (qb + 1);
    const int myMax = (qrow0 + 15) >> 6;
    for (int kb = 0; kb < nU; kb++) {
      u16x8 k0 = *(const u16x8*)(const void*)(K + (size_t)(kb * 64 + rk0) * (NKV * HD) + kvh * HD + ck0 * 8);
      u16x8 k1 = *(const u16x8*)(const void*)(K + (size_t)(kb * 64 + rk0 + 32) * (NKV * HD) + kvh * HD + ck0 * 8);
      u16x8 v0 = *(const u16x8*)(const void*)(Vh + (size_t)rv0 * NTOK + kb * 64 + cv0 * 8);
      u16x8 v1 = *(const u16x8*)(const void*)(Vh + (size_t)(rv0 + 64) * NTOK + kb * 64 + cv0 * 8);
      __syncthreads();
      *(u16x8*)(void*)(sK + rk0 * 136 + ck0 * 8) = k0;
      *(u16x8*)(void*)(sK + (rk0 + 32) * 136 + ck0 * 8) = k1;
      *(u16x8*)(void*)(sV + rv0 * 72 + cv0 * 8) = v0;
      *(u16x8*)(void*)(sV + (rv0 + 64) * 72 + cv0 * 8) = v1;
      __syncthreads();
      if (kb <= myMax) {
        f32x4 s[4] = {};
        for (int ks = 0; ks < 4; ks++)
          for (int nt = 0; nt < 4; nt++) {
            bf16x8 kf = *(const bf16x8*)(const void*)(sK + (nt * 16 + l16) * 136 + ks * 32 + quad * 8);
            s[nt] = __builtin_amdgcn_mfma_f32_16x16x32_bf16(qf[ks], kf, s[nt], 0, 0, 0);
          }
        const int qg = qrow0 + quad * 4;
        for (int nt = 0; nt < 4; nt++) {
          int tok = kb * 64 + nt * 16 + l16;
          for (int r = 0; r < 4; r++) {
            float e = __expf(s[nt][r]);
            float pv = (tok <= qg + r) ? e : 0.0f;
            l_r[r] += pv;
            myP[(quad * 4 + r) * 72 + nt * 16 + l16] = f2bf(pv);
          }
        }
        asm volatile("s_waitcnt lgkmcnt(0)" ::: "memory");
        for (int ks = 0; ks < 2; ks++) {
          bf16x8 pf = *(const bf16x8*)(const void*)(myP + l16 * 72 + ks * 32 + quad * 8);
          for (int nt = 0; nt < 8; nt++) {
            bf16x8 vf = *(const bf16x8*)(const void*)(sV + (nt * 16 + l16) * 72 + ks * 32 + quad * 8);
            accO[nt] = __builtin_amdgcn_mfma_f32_16x16x32_bf16(pf, vf, accO[nt], 0, 0, 0);
          }
        }
      }
    }
    float inv[4];
    for (int r = 0; r < 4; r++) {
      float t = l_r[r];
      t += __shfl_xor(t, 1);
      t += __shfl_xor(t, 2);
      t += __shfl_xor(t, 4);
      t += __shfl_xor(t, 8);
      inv[r] = 1.0f / t;
    }
    for (int nt = 0; nt < 8; nt++)
      for (int r = 0; r < 4; r++)
        O[(size_t)(qrow0 + quad * 4 + r) * (NQ * HD) + h * HD + nt * 16 + l16] =
            f2bf(accO[nt][r] * inv[r]);
  }
}

extern "C" void kernel_launch(void* const* d_in, const int* in_sizes, int n_in,
                              void* d_out, int out_size, void* d_ws, size_t ws_size,
                              hipStream_t stream) {
  const float* hidden = (const float*)d_in[0];
  const int* positions = (const int*)d_in[1];
  const float* Wq = (const float*)d_in[2];
  const float* Wk = (const float*)d_in[3];
  const float* Wv = (const float*)d_in[4];
  const float* Wo = (const float*)d_in[5];
  const float* qw = (const float*)d_in[6];
  const float* kw = (const float*)d_in[7];
  char* ws = (char*)d_ws;
  u16* hid_bf  = (u16*)(ws);                    // 16 MB
  u16* WqkvT   = (u16*)(ws + 16777216);         // 48 MB
  u16* WoT     = (u16*)(ws + 67108864);         // 32 MB
  float* qkvf  = (float*)(ws + 100663296);      // 48 MB
  u16* Qn      = (u16*)(ws + 150994944);        // 16 MB
  u16* Kn      = (u16*)(ws + 167772160);        //  4 MB
  u16* Vt      = (u16*)(ws + 171966464);        //  4 MB
  u16* AO      = (u16*)(ws + 176160768);        // 16 MB
  float* outp  = (float*)d_out;

  cvt_hidden<<<NTOK * HIDDEN / 4 / 256, 256, 0, stream>>>(hidden, hid_bf, NTOK * HIDDEN / 4);
  transpose_cvt<<<dim3(64, 64), 256, 0, stream>>>(Wq, WqkvT, 4096, 4096);
  transpose_cvt<<<dim3(16, 64), 256, 0, stream>>>(Wk, WqkvT + (size_t)4096 * 4096, 4096, 1024);
  transpose_cvt<<<dim3(16, 64), 256, 0, stream>>>(Wv, WqkvT + (size_t)5120 * 4096, 4096, 1024);
  transpose_cvt<<<dim3(64, 64), 256, 0, stream>>>(Wo, WoT, 4096, 4096);
  gemm_bt<<<dim3(48, 16), 256, 0, stream>>>(hid_bf, WqkvT, qkvf, 2048, 6144, 4096);
  normrope<<<dim3(40, 512), 256, 0, stream>>>(qkvf, positions, qw, kw, Qn, Kn);
  vtrans<<<dim3(32, 8), 256, 0, stream>>>(qkvf, Vt);
  flash2<<<dim3(8, 32), 512, 0, stream>>>(Qn, Kn, Vt, AO);
  gemm_bt<<<dim3(32, 16), 256, 0, stream>>>(AO, WoT, outp, 2048, 4096, 4096);
}